// Round 5
// baseline (471.600 us; speedup 1.0000x reference)
//
#include <hip/hip_runtime.h>

typedef unsigned short u16;
typedef short v8s __attribute__((ext_vector_type(8)));
typedef float v4f __attribute__((ext_vector_type(4)));
typedef u16  v4u __attribute__((ext_vector_type(4)));

__device__ __forceinline__ float bf2f(u16 h){ return __uint_as_float(((unsigned)h)<<16); }
__device__ __forceinline__ u16 f2bf(float f){
  unsigned u = __float_as_uint(f);
  u += 0x7FFFu + ((u>>16)&1u);
  return (u16)(u>>16);
}
__device__ __forceinline__ float siluf(float x){ return x/(1.f+__expf(-x)); }
__device__ __forceinline__ float softplusf(float x){
  return (x>15.f) ? x : __logf(1.f+__expf(x));
}

// ---------------------------------------------------------------------------
// Setup mega-kernel: 4 independent jobs by block range.
//  [0,32)          zero stats slots for layers 1..4 (8192 f32)
//  [32,10016)      f32->bf16 weight cvt; ln_g folded into W_inproj (W' = g*W)
//  [10016,13088)   prep: sg[e]=sum_k g*W, cb[e]=sum_k beta*W  (per layer row)
//  [13088,14112)   input MLP -> h (f32) + hb (bf16) + stats[0] (S1,S2 per row)
// ---------------------------------------------------------------------------
struct SetupP {
  const float *x,*w_in,*b_in,*ln_g,*ln_b,*W_inproj,*W_xproj,*W_dt,*W_outproj;
  u16 *wIn,*wX,*wDt,*wOut;
  float *sg,*cb,*stats,*h;
  u16 *hb;
};

__global__ __launch_bounds__(256) void setup_kernel(SetupP sp)
{
  __shared__ float red[8];
  const int blk = blockIdx.x, t = threadIdx.x;
  if(blk < 32){
    int idx = blk*256 + t;              // 8192 stats entries, layers 1..4
    sp.stats[2048 + idx] = 0.f;
    return;
  }
  if(blk < 10016){                      // cvt
    const int c0=6291456, c1=c0+589824, c2=c1+196608;
    int i4 = ((blk-32)*256 + t)*4;
    float4 v; u16* dst;
    if(i4 < c0){
      v = *(const float4*)(sp.W_inproj + i4);
      int k = i4 & 511, le = i4 >> 9, l = le/3072;
      const float* gg = sp.ln_g + l*512 + k;
      v.x*=gg[0]; v.y*=gg[1]; v.z*=gg[2]; v.w*=gg[3];
      dst = sp.wIn + i4;
    } else if(i4 < c1){ int o=i4-c0; v=*(const float4*)(sp.W_xproj+o);   dst=sp.wX+o; }
    else if(i4 < c2){   int o=i4-c1; v=*(const float4*)(sp.W_dt+o);      dst=sp.wDt+o; }
    else {              int o=i4-c2; v=*(const float4*)(sp.W_outproj+o); dst=sp.wOut+o; }
    v4u pk={ f2bf(v.x), f2bf(v.y), f2bf(v.z), f2bf(v.w) };
    *(v4u*)dst = pk;
    return;
  }
  if(blk < 13088){                      // prep sg/cb
    int wid=t>>6, lane=t&63;
    int ridx = (blk-10016)*4 + wid;     // [0,12288) = l*3072+e
    int l = ridx/3072;
    const float* wr = sp.W_inproj + (size_t)ridx*512;
    const float* gg = sp.ln_g + l*512;
    const float* bb = sp.ln_b + l*512;
    float sgv=0.f, cbv=0.f;
#pragma unroll
    for(int i=0;i<8;i++){ int k=lane*8+i; float w=wr[k]; sgv+=gg[k]*w; cbv+=bb[k]*w; }
#pragma unroll
    for(int off=1; off<64; off<<=1){ sgv+=__shfl_xor(sgv,off); cbv+=__shfl_xor(cbv,off); }
    if(lane==0){ sp.sg[ridx]=sgv; sp.cb[ridx]=cbv; }
    return;
  }
  // input MLP (full row per block so stats need no atomics)
  int b = blk - 13088;
  const float* xr = sp.x + b*68 + 4;
  float v0, v1;
  {
    const float* wr = sp.w_in + t*64;
    float a = sp.b_in[t];
#pragma unroll
    for(int f=0; f<64; f++) a += xr[f]*wr[f];
    v0 = fmaxf(a, 0.f);
  }
  {
    const float* wr = sp.w_in + (t+256)*64;
    float a = sp.b_in[t+256];
#pragma unroll
    for(int f=0; f<64; f++) a += xr[f]*wr[f];
    v1 = fmaxf(a, 0.f);
  }
  sp.h[b*512+t] = v0;     sp.h[b*512+256+t] = v1;
  sp.hb[b*512+t]= f2bf(v0); sp.hb[b*512+256+t]= f2bf(v1);
  float s = v0+v1, s2 = v0*v0+v1*v1;
#pragma unroll
  for(int off=32; off; off>>=1){ s += __shfl_down(s,off); s2 += __shfl_down(s2,off); }
  if((t&63)==0){ red[(t>>6)*2]=s; red[(t>>6)*2+1]=s2; }
  __syncthreads();
  if(t==0){
    sp.stats[b*2]   = red[0]+red[2]+red[4]+red[6];
    sp.stats[b*2+1] = red[1]+red[3]+red[5]+red[7];
  }
}

// ---------------------------------------------------------------------------
// G1 with algebraic fused LayerNorm: acc = hb @ W'^T (W'=g*W bf16);
// val = rstd_b*(acc - mu_b*sg[e]) + cb[e]; then conv-tap/silu epilogue.
// grid (48 nt, 16 mt), K=512 (16 iters), pure bf16 v8s staging, depth-2 pf.
// ---------------------------------------------------------------------------
__global__ __launch_bounds__(256) void gemm1_ln(
  const u16* __restrict__ hb, const u16* __restrict__ Wp,
  const float* __restrict__ sg, const float* __restrict__ cb,
  const float* __restrict__ st,
  const float* __restrict__ convw, const float* __restrict__ convb,
  u16* __restrict__ u, u16* __restrict__ zs)
{
  __shared__ u16 As[64*40], Bs[64*40];
  const int tid=threadIdx.x, lane=tid&63, wid=tid>>6;
  const int wm=wid>>1, wn=wid&1;
  const int qd=lane>>4, lr=lane&15;
  const int m0=blockIdx.y*64, n0=blockIdx.x*64;

  v4f acc[2][2];
#pragma unroll
  for(int i=0;i<2;i++)
#pragma unroll
    for(int j=0;j<2;j++) acc[i][j]=v4f{0.f,0.f,0.f,0.f};

  v8s ra[2], rb[2];
  const int r_=tid>>2, kg_=tid&3;
  auto loadA=[&](int set,int kk){ ra[set]=*(const v8s*)(hb+(size_t)(m0+r_)*512+kk+kg_*8); };
  auto loadB=[&](int set,int kk){ rb[set]=*(const v8s*)(Wp+(size_t)(n0+r_)*512+kk+kg_*8); };
  loadA(0,0); loadB(0,0); loadA(1,32); loadB(1,32);

  for(int it=0; it<16; it++){
    const int kk=it*32, set=it&1;
    __syncthreads();
    *(v8s*)(As+r_*40+kg_*8)=ra[set];
    *(v8s*)(Bs+r_*40+kg_*8)=rb[set];
    __syncthreads();
    if(it+2<16){ loadA(set,kk+64); loadB(set,kk+64); }
    v8s af[2], bfv[2];
#pragma unroll
    for(int i=0;i<2;i++) af[i] =*(const v8s*)(As+(wm*32+i*16+lr)*40+qd*8);
#pragma unroll
    for(int j=0;j<2;j++) bfv[j]=*(const v8s*)(Bs+(wn*32+j*16+lr)*40+qd*8);
#pragma unroll
    for(int i=0;i<2;i++)
#pragma unroll
      for(int j=0;j<2;j++)
        acc[i][j]=__builtin_amdgcn_mfma_f32_16x16x32_bf16(af[i],bfv[j],acc[i][j],0,0,0);
  }

#pragma unroll
  for(int i=0;i<2;i++){
    const int gb0=m0+wm*32+i*16+qd*4;
#pragma unroll
    for(int r=0;r<4;r++){
      const int gb=gb0+r;
      float S1=st[gb*2], S2=st[gb*2+1];
      float mu=S1*(1.f/512.f);
      float rs=rsqrtf(S2*(1.f/512.f)-mu*mu+1e-5f);
#pragma unroll
      for(int j=0;j<2;j++){
        const int ge=n0+wn*32+j*16+lr;
        float val = rs*(acc[i][j][r] - mu*sg[ge]) + cb[ge];
        if(ge<1536){
          u[(size_t)gb*1536+ge]=f2bf(siluf(val*convw[ge*4+3]+convb[ge]));
        }else{
          zs[(size_t)gb*1536+(ge-1536)]=f2bf(siluf(val));
        }
      }
    }
  }
}

// ---------------------------------------------------------------------------
// Fused G2 + sdt + G3. grid (6 nslice, 16 mt).
// Phase A: full x_dbl[64x96] = u @ W_xproj^T (K=1536, redundant across nslice)
// Phase B: s[b]=dot(Bm,Cm), dt->bf16 (LDS only)
// Phase C: 4 n-tiles of y = u*(softplus(dt@W_dt^T+bdt)*s + Dp)*zs
// ---------------------------------------------------------------------------
__global__ __launch_bounds__(256) void gemm23(
  const u16* __restrict__ u, const u16* __restrict__ zs,
  const u16* __restrict__ wX, const u16* __restrict__ wDt,
  const float* __restrict__ bdt, const float* __restrict__ Dp,
  u16* __restrict__ y)
{
  __shared__ u16 As[64*40];
  __shared__ u16 Bs[96*40];
  __shared__ float Ot[64*100];
  __shared__ u16 dts[64*40];
  __shared__ float sbl[64];
  const int tid=threadIdx.x, lane=tid&63, wid=tid>>6;
  const int wm=wid>>1, wn=wid&1;
  const int qd=lane>>4, lr=lane&15;
  const int m0=blockIdx.y*64;

  // ---- phase A ----
  v4f acc[2][3];
#pragma unroll
  for(int i=0;i<2;i++)
#pragma unroll
    for(int j=0;j<3;j++) acc[i][j]=v4f{0.f,0.f,0.f,0.f};

  const int r_=tid>>2, kg_=tid&3;
  v8s ra[2], rbv[2][2];
  auto loadA=[&](int set,int kk){ ra[set]=*(const v8s*)(u+(size_t)(m0+r_)*1536+kk+kg_*8); };
  auto loadB=[&](int set,int kk){
#pragma unroll
    for(int ii=0;ii<2;ii++){ int s=tid+ii*256;
      if(s<384){ int r=s>>2, kg=s&3;
        rbv[set][ii]=*(const v8s*)(wX+(size_t)r*1536+kk+kg*8); } }
  };
  loadA(0,0); loadB(0,0); loadA(1,32); loadB(1,32);

  for(int it=0; it<48; it++){
    const int kk=it*32, set=it&1;
    __syncthreads();
    *(v8s*)(As+r_*40+kg_*8)=ra[set];
#pragma unroll
    for(int ii=0;ii<2;ii++){ int s=tid+ii*256;
      if(s<384){ int r=s>>2, kg=s&3; *(v8s*)(Bs+r*40+kg*8)=rbv[set][ii]; } }
    __syncthreads();
    if(it+2<48){ loadA(set,kk+64); loadB(set,kk+64); }
    v8s af[2], bfv[3];
#pragma unroll
    for(int i=0;i<2;i++) af[i] =*(const v8s*)(As+(wm*32+i*16+lr)*40+qd*8);
#pragma unroll
    for(int j=0;j<3;j++) bfv[j]=*(const v8s*)(Bs+(wn*48+j*16+lr)*40+qd*8);
#pragma unroll
    for(int i=0;i<2;i++)
#pragma unroll
      for(int j=0;j<3;j++)
        acc[i][j]=__builtin_amdgcn_mfma_f32_16x16x32_bf16(af[i],bfv[j],acc[i][j],0,0,0);
  }

  // ---- phase B ----
#pragma unroll
  for(int i=0;i<2;i++)
#pragma unroll
    for(int j=0;j<3;j++){
      int lr0=wm*32+i*16+qd*4, lc=wn*48+j*16+lr;
#pragma unroll
      for(int r=0;r<4;r++) Ot[(lr0+r)*100+lc]=acc[i][j][r];
    }
  __syncthreads();
  {
    int r4=tid>>2, sub=tid&3;
    const float* orow = Ot + r4*100;
    float s_=0.f;
#pragma unroll
    for(int i=0;i<8;i++){ int n=sub*8+i; s_ += orow[32+n]*orow[64+n]; }
    s_ += __shfl_xor(s_,1); s_ += __shfl_xor(s_,2);
    if(sub==0) sbl[r4]=s_;
#pragma unroll
    for(int i=0;i<8;i++){ int c=sub*8+i; dts[r4*40+c]=f2bf(orow[c]); }
  }

  // ---- phase C ----
  for(int nt=0; nt<4; nt++){
    const int n0 = (blockIdx.x*4+nt)*64;
    __syncthreads();
    *(v8s*)(Bs+r_*40+kg_*8) = *(const v8s*)(wDt+(size_t)(n0+r_)*32+kg_*8);
    __syncthreads();
    v4f a2[2][2];
#pragma unroll
    for(int i=0;i<2;i++)
#pragma unroll
      for(int j=0;j<2;j++) a2[i][j]=v4f{0.f,0.f,0.f,0.f};
    v8s af[2], bfv[2];
#pragma unroll
    for(int i=0;i<2;i++) af[i] =*(const v8s*)(dts+(wm*32+i*16+lr)*40+qd*8);
#pragma unroll
    for(int j=0;j<2;j++) bfv[j]=*(const v8s*)(Bs+(wn*32+j*16+lr)*40+qd*8);
#pragma unroll
    for(int i=0;i<2;i++)
#pragma unroll
      for(int j=0;j<2;j++)
        a2[i][j]=__builtin_amdgcn_mfma_f32_16x16x32_bf16(af[i],bfv[j],a2[i][j],0,0,0);
#pragma unroll
    for(int i=0;i<2;i++){
      const int lb0=wm*32+i*16+qd*4;
#pragma unroll
      for(int r=0;r<4;r++){
        const int gb=m0+lb0+r;
        const float sv=sbl[lb0+r];
#pragma unroll
        for(int j=0;j<2;j++){
          const int ge=n0+wn*32+j*16+lr;
          float delta=softplusf(a2[i][j][r]+bdt[ge]);
          float uu=bf2f(u[(size_t)gb*1536+ge]);
          float zz=bf2f(zs[(size_t)gb*1536+ge]);
          y[(size_t)gb*1536+ge]=f2bf(uu*(delta*sv+Dp[ge])*zz);
        }
      }
    }
  }
}

// ---------------------------------------------------------------------------
// G4: y @ W_outproj^T (K=1536, 48 iters), epilogue: h += acc (f32), write
// bf16 h copy, accumulate next-layer LN stats via atomics.
// grid (8 nt, 16 mt).
// ---------------------------------------------------------------------------
__global__ __launch_bounds__(256) void gemm4(
  const u16* __restrict__ yv, const u16* __restrict__ wO,
  float* __restrict__ h, u16* __restrict__ hb, float* __restrict__ stn)
{
  __shared__ u16 As[64*40], Bs[64*40];
  const int tid=threadIdx.x, lane=tid&63, wid=tid>>6;
  const int wm=wid>>1, wn=wid&1;
  const int qd=lane>>4, lr=lane&15;
  const int m0=blockIdx.y*64, n0=blockIdx.x*64;

  v4f acc[2][2];
#pragma unroll
  for(int i=0;i<2;i++)
#pragma unroll
    for(int j=0;j<2;j++) acc[i][j]=v4f{0.f,0.f,0.f,0.f};

  const int r_=tid>>2, kg_=tid&3;
  v8s ra[2], rb[2];
  auto loadA=[&](int set,int kk){ ra[set]=*(const v8s*)(yv+(size_t)(m0+r_)*1536+kk+kg_*8); };
  auto loadB=[&](int set,int kk){ rb[set]=*(const v8s*)(wO+(size_t)(n0+r_)*1536+kk+kg_*8); };
  loadA(0,0); loadB(0,0); loadA(1,32); loadB(1,32);

  for(int it=0; it<48; it++){
    const int kk=it*32, set=it&1;
    __syncthreads();
    *(v8s*)(As+r_*40+kg_*8)=ra[set];
    *(v8s*)(Bs+r_*40+kg_*8)=rb[set];
    __syncthreads();
    if(it+2<48){ loadA(set,kk+64); loadB(set,kk+64); }
    v8s af[2], bfv[2];
#pragma unroll
    for(int i=0;i<2;i++) af[i] =*(const v8s*)(As+(wm*32+i*16+lr)*40+qd*8);
#pragma unroll
    for(int j=0;j<2;j++) bfv[j]=*(const v8s*)(Bs+(wn*32+j*16+lr)*40+qd*8);
#pragma unroll
    for(int i=0;i<2;i++)
#pragma unroll
      for(int j=0;j<2;j++)
        acc[i][j]=__builtin_amdgcn_mfma_f32_16x16x32_bf16(af[i],bfv[j],acc[i][j],0,0,0);
  }

#pragma unroll
  for(int i=0;i<2;i++){
    const int gb0=m0+wm*32+i*16+qd*4;
#pragma unroll
    for(int r=0;r<4;r++){
      const int gb=gb0+r;
      float rs1=0.f, rs2=0.f;
#pragma unroll
      for(int j=0;j<2;j++){
        const int ge=n0+wn*32+j*16+lr;
        const size_t idx=(size_t)gb*512+ge;
        float hv = h[idx] + acc[i][j][r];
        h[idx]=hv; hb[idx]=f2bf(hv);
        rs1+=hv; rs2+=hv*hv;
      }
      rs1+=__shfl_xor(rs1,1); rs2+=__shfl_xor(rs2,1);
      rs1+=__shfl_xor(rs1,2); rs2+=__shfl_xor(rs2,2);
      rs1+=__shfl_xor(rs1,4); rs2+=__shfl_xor(rs2,4);
      rs1+=__shfl_xor(rs1,8); rs2+=__shfl_xor(rs2,8);
      if(lr==0){ atomicAdd(stn+gb*2, rs1); atomicAdd(stn+gb*2+1, rs2); }
    }
  }
}

// ---------------------------------------------------------------------------
// Head: lg/gate/MLP/sigmoid from final f32 residual h. One block per row.
// ---------------------------------------------------------------------------
__global__ __launch_bounds__(256) void head_kernel(
  const float* __restrict__ x, const float* __restrict__ h,
  const float* __restrict__ wlog, const float* __restrict__ blog,
  const float* __restrict__ wg, const float* __restrict__ bg,
  const float* __restrict__ wh1, const float* __restrict__ bh1,
  const float* __restrict__ wh2, const float* __restrict__ bh2,
  float* __restrict__ out)
{
  int b = blockIdx.x, t = threadIdx.x;
  __shared__ float fused[512];
  __shared__ float part[256];
  __shared__ float z1s[32];
  float lgin = x[b*68+0]*wlog[0] + x[b*68+1]*wlog[1]
             + x[b*68+2]*wlog[2] + x[b*68+3]*wlog[3] + blog[0];
  float lg = 1.f/(1.f+__expf(-lgin));
  for(int d=t; d<512; d+=256)
    fused[d] = h[(size_t)b*512+d]*(lg*wg[d] + bg[d]);
  __syncthreads();
  int j = t&31, c = t>>5;
  float p = 0.f;
#pragma unroll
  for(int i=0;i<64;i++){ int d = c*64+i; p += fused[d]*wh1[j*512+d]; }
  part[t] = p;
  __syncthreads();
  if(t < 32){
    float z = bh1[t];
#pragma unroll
    for(int cc=0; cc<8; cc++) z += part[cc*32+t];
    z1s[t] = fmaxf(z, 0.f);
  }
  __syncthreads();
  if(t==0){
    float lo = bh2[0];
#pragma unroll
    for(int jj=0;jj<32;jj++) lo += z1s[jj]*wh2[jj];
    out[b] = 1.f/(1.f+__expf(-lo));
  }
}

// ---------------------------------------------------------------------------
extern "C" void kernel_launch(void* const* d_in, const int* in_sizes, int n_in,
                              void* d_out, int out_size, void* d_ws, size_t ws_size,
                              hipStream_t stream)
{
  const float* x        = (const float*)d_in[0];
  const float* w_in     = (const float*)d_in[1];
  const float* b_in     = (const float*)d_in[2];
  const float* ln_g     = (const float*)d_in[3];
  const float* ln_b     = (const float*)d_in[4];
  const float* W_inproj = (const float*)d_in[5];
  const float* conv_w   = (const float*)d_in[6];
  const float* conv_b   = (const float*)d_in[7];
  const float* W_xproj  = (const float*)d_in[8];
  const float* W_dt     = (const float*)d_in[9];
  const float* b_dt     = (const float*)d_in[10];
  // d_in[11] A_log: dead — scan is a single step from h0=0
  const float* D_skip   = (const float*)d_in[12];
  const float* W_outproj= (const float*)d_in[13];
  const float* w_log    = (const float*)d_in[14];
  const float* b_log    = (const float*)d_in[15];
  const float* W_gate   = (const float*)d_in[16];
  const float* b_gate   = (const float*)d_in[17];
  const float* W_h1     = (const float*)d_in[18];
  const float* b_h1     = (const float*)d_in[19];
  const float* W_h2     = (const float*)d_in[20];
  const float* b_h2     = (const float*)d_in[21];
  float* out = (float*)d_out;
  (void)in_sizes; (void)n_in; (void)out_size; (void)ws_size;

  char* ws = (char*)d_ws;
  size_t off = 0;
  auto alloc = [&](size_t bytes)->char*{
    char* p = ws + off; off = (off + bytes + 255) & ~(size_t)255; return p; };
  u16*   wIn  = (u16*)  alloc(6291456u*2);   // W' = g*W_inproj, bf16
  u16*   wX   = (u16*)  alloc(589824u*2);
  u16*   wDt  = (u16*)  alloc(196608u*2);
  u16*   wOut = (u16*)  alloc(3145728u*2);
  float* sg   = (float*)alloc(12288u*4);     // per-layer sum g*W
  float* cb   = (float*)alloc(12288u*4);     // per-layer sum beta*W
  float* stats= (float*)alloc(10240u*4);     // [5][1024][2] row sums
  float* h    = (float*)alloc(524288u*4);    // f32 residual
  u16*   hb   = (u16*)  alloc(524288u*2);    // bf16 copy of h
  u16*   u    = (u16*)  alloc(1572864u*2);
  u16*   zs   = (u16*)  alloc(1572864u*2);
  u16*   y    = (u16*)  alloc(1572864u*2);

  SetupP sp;
  sp.x=x; sp.w_in=w_in; sp.b_in=b_in; sp.ln_g=ln_g; sp.ln_b=ln_b;
  sp.W_inproj=W_inproj; sp.W_xproj=W_xproj; sp.W_dt=W_dt; sp.W_outproj=W_outproj;
  sp.wIn=wIn; sp.wX=wX; sp.wDt=wDt; sp.wOut=wOut;
  sp.sg=sg; sp.cb=cb; sp.stats=stats; sp.h=h; sp.hb=hb;

  setup_kernel<<<14112,256,0,stream>>>(sp);

  for(int l=0;l<4;l++){
    gemm1_ln<<<dim3(48,16),256,0,stream>>>(
      hb, wIn+(size_t)l*1572864, sg+l*3072, cb+l*3072, stats+l*2048,
      conv_w+l*6144, conv_b+l*1536, u, zs);
    gemm23<<<dim3(6,16),256,0,stream>>>(
      u, zs, wX+(size_t)l*147456, wDt+(size_t)l*49152,
      b_dt+l*1536, D_skip+l*1536, y);
    gemm4<<<dim3(8,16),256,0,stream>>>(
      y, wOut+(size_t)l*786432, h, hb, stats+(l+1)*2048);
  }

  head_kernel<<<1024,256,0,stream>>>(x, h, w_log, b_log, W_gate, b_gate,
                                     W_h1, b_h1, W_h2, b_h2, out);
}

// Round 6
// 343.484 us; speedup vs baseline: 1.3730x; 1.3730x over previous
//
#include <hip/hip_runtime.h>

typedef unsigned short u16;
typedef short v8s __attribute__((ext_vector_type(8)));
typedef float v4f __attribute__((ext_vector_type(4)));
typedef u16  v4u __attribute__((ext_vector_type(4)));

__device__ __forceinline__ float bf2f(u16 h){ return __uint_as_float(((unsigned)h)<<16); }
__device__ __forceinline__ u16 f2bf(float f){
  unsigned u = __float_as_uint(f);
  u += 0x7FFFu + ((u>>16)&1u);
  return (u16)(u>>16);
}
__device__ __forceinline__ float siluf(float x){ return x/(1.f+__expf(-x)); }
__device__ __forceinline__ float softplusf(float x){
  return (x>15.f) ? x : __logf(1.f+__expf(x));
}

// ---------------------------------------------------------------------------
// Setup mega-kernel (4 jobs by block range):
//  [0,32)        zero LN-stats slots for layers 1..4
//  [32,10016)    f32->bf16 weight cvt; ln_g folded into W_inproj (W'=g*W)
//  [10016,13088) prep sg[e]=sum_k g*W, cb[e]=sum_k beta*W
//  [13088,14112) input MLP -> h(f32) + hb(bf16) + stats[0] (S1,S2 per row)
// ---------------------------------------------------------------------------
struct SetupP {
  const float *x,*w_in,*b_in,*ln_g,*ln_b,*W_inproj,*W_xproj,*W_dt,*W_outproj;
  u16 *wIn,*wX,*wDt,*wOut;
  float *sg,*cb,*stats,*h;
  u16 *hb;
};

__global__ __launch_bounds__(256) void setup_kernel(SetupP sp)
{
  __shared__ float red[8];
  const int blk = blockIdx.x, t = threadIdx.x;
  if(blk < 32){
    sp.stats[2048 + blk*256 + t] = 0.f;
    return;
  }
  if(blk < 10016){
    const int c0=6291456, c1=c0+589824, c2=c1+196608;
    int i4 = ((blk-32)*256 + t)*4;
    float4 v; u16* dst;
    if(i4 < c0){
      v = *(const float4*)(sp.W_inproj + i4);
      int k = i4 & 511, l = (i4>>9)/3072;
      const float* gg = sp.ln_g + l*512 + k;
      v.x*=gg[0]; v.y*=gg[1]; v.z*=gg[2]; v.w*=gg[3];
      dst = sp.wIn + i4;
    } else if(i4 < c1){ int o=i4-c0; v=*(const float4*)(sp.W_xproj+o);   dst=sp.wX+o; }
    else if(i4 < c2){   int o=i4-c1; v=*(const float4*)(sp.W_dt+o);      dst=sp.wDt+o; }
    else {              int o=i4-c2; v=*(const float4*)(sp.W_outproj+o); dst=sp.wOut+o; }
    v4u pk={ f2bf(v.x), f2bf(v.y), f2bf(v.z), f2bf(v.w) };
    *(v4u*)dst = pk;
    return;
  }
  if(blk < 13088){
    int wid=t>>6, lane=t&63;
    int ridx = (blk-10016)*4 + wid;     // l*3072+e
    int l = ridx/3072;
    const float* wr = sp.W_inproj + (size_t)ridx*512;
    const float* gg = sp.ln_g + l*512;
    const float* bb = sp.ln_b + l*512;
    float sgv=0.f, cbv=0.f;
#pragma unroll
    for(int i=0;i<8;i++){ int k=lane*8+i; float w=wr[k]; sgv+=gg[k]*w; cbv+=bb[k]*w; }
#pragma unroll
    for(int off=1; off<64; off<<=1){ sgv+=__shfl_xor(sgv,off); cbv+=__shfl_xor(cbv,off); }
    if(lane==0){ sp.sg[ridx]=sgv; sp.cb[ridx]=cbv; }
    return;
  }
  int b = blk - 13088;
  const float* xr = sp.x + b*68 + 4;
  float v0, v1;
  {
    const float* wr = sp.w_in + t*64;
    float a = sp.b_in[t];
#pragma unroll
    for(int f=0; f<64; f++) a += xr[f]*wr[f];
    v0 = fmaxf(a, 0.f);
  }
  {
    const float* wr = sp.w_in + (t+256)*64;
    float a = sp.b_in[t+256];
#pragma unroll
    for(int f=0; f<64; f++) a += xr[f]*wr[f];
    v1 = fmaxf(a, 0.f);
  }
  sp.h[b*512+t] = v0;       sp.h[b*512+256+t] = v1;
  sp.hb[b*512+t]= f2bf(v0); sp.hb[b*512+256+t]= f2bf(v1);
  float s = v0+v1, s2 = v0*v0+v1*v1;
#pragma unroll
  for(int off=32; off; off>>=1){ s += __shfl_down(s,off); s2 += __shfl_down(s2,off); }
  if((t&63)==0){ red[(t>>6)*2]=s; red[(t>>6)*2+1]=s2; }
  __syncthreads();
  if(t==0){
    sp.stats[b*2]   = red[0]+red[2]+red[4]+red[6];
    sp.stats[b*2+1] = red[1]+red[3]+red[5]+red[7];
  }
}

// ---------------------------------------------------------------------------
// G1, algebraic fused LN: acc = hb @ (g*W)^T; val = rs*(acc - mu*sg) + cb.
// grid (48,16), 64x64 tile, K=512; manual x2-unrolled depth-2 prefetch.
// ---------------------------------------------------------------------------
__global__ __launch_bounds__(256) void gemm1_ln(
  const u16* __restrict__ hb, const u16* __restrict__ Wp,
  const float* __restrict__ sg, const float* __restrict__ cb,
  const float* __restrict__ st,
  const float* __restrict__ convw, const float* __restrict__ convb,
  u16* __restrict__ u, u16* __restrict__ zs)
{
  __shared__ u16 As[64*40], Bs[64*40];
  const int tid=threadIdx.x, lane=tid&63, wid=tid>>6;
  const int wm=wid>>1, wn=wid&1, qd=lane>>4, lr=lane&15;
  const int m0=blockIdx.y*64, n0=blockIdx.x*64;
  const int r_=tid>>2, kg_=tid&3;
  const u16* Ap = hb + (size_t)(m0+r_)*512 + kg_*8;
  const u16* Bp = Wp + (size_t)(n0+r_)*512 + kg_*8;
  u16* Asw = As + r_*40 + kg_*8;
  u16* Bsw = Bs + r_*40 + kg_*8;

  v4f acc[2][2];
#pragma unroll
  for(int i=0;i<2;i++)
#pragma unroll
    for(int j=0;j<2;j++) acc[i][j]=v4f{0.f,0.f,0.f,0.f};

  auto domfma=[&](){
    v8s af[2], bfv[2];
#pragma unroll
    for(int i=0;i<2;i++) af[i] =*(const v8s*)(As+(wm*32+i*16+lr)*40+qd*8);
#pragma unroll
    for(int j=0;j<2;j++) bfv[j]=*(const v8s*)(Bs+(wn*32+j*16+lr)*40+qd*8);
#pragma unroll
    for(int i=0;i<2;i++)
#pragma unroll
      for(int j=0;j<2;j++)
        acc[i][j]=__builtin_amdgcn_mfma_f32_16x16x32_bf16(af[i],bfv[j],acc[i][j],0,0,0);
  };

  v8s a0=*(const v8s*)(Ap),    b0=*(const v8s*)(Bp);
  v8s a1=*(const v8s*)(Ap+32), b1=*(const v8s*)(Bp+32);
  for(int it=0; it<16; it+=2){
    const int kk=it*32;
    __syncthreads();
    *(v8s*)Asw=a0; *(v8s*)Bsw=b0;
    __syncthreads();
    if(it+2<16){ a0=*(const v8s*)(Ap+kk+64); b0=*(const v8s*)(Bp+kk+64); }
    domfma();
    __syncthreads();
    *(v8s*)Asw=a1; *(v8s*)Bsw=b1;
    __syncthreads();
    if(it+2<16){ a1=*(const v8s*)(Ap+kk+96); b1=*(const v8s*)(Bp+kk+96); }
    domfma();
  }

#pragma unroll
  for(int i=0;i<2;i++){
    const int gb0=m0+wm*32+i*16+qd*4;
#pragma unroll
    for(int r=0;r<4;r++){
      const int gb=gb0+r;
      float S1=st[gb*2], S2=st[gb*2+1];
      float mu=S1*(1.f/512.f);
      float rs=rsqrtf(S2*(1.f/512.f)-mu*mu+1e-5f);
#pragma unroll
      for(int j=0;j<2;j++){
        const int ge=n0+wn*32+j*16+lr;
        float val = rs*(acc[i][j][r] - mu*sg[ge]) + cb[ge];
        if(ge<1536){
          u[(size_t)gb*1536+ge]=f2bf(siluf(val*convw[ge*4+3]+convb[ge]));
        }else{
          zs[(size_t)gb*1536+(ge-1536)]=f2bf(siluf(val));
        }
      }
    }
  }
}

// ---------------------------------------------------------------------------
// G2: u @ W_xproj^T, split-K=8 -> xpart[z][1024][96]. grid (8 z, 16 mt).
// 64x96 tile, Klen=192 (6 halves, x2-unrolled).
// ---------------------------------------------------------------------------
__global__ __launch_bounds__(256) void gemm2(
  const u16* __restrict__ A, const u16* __restrict__ wX,
  float* __restrict__ xpart)
{
  __shared__ u16 As[64*40];
  __shared__ u16 Bs[96*40];
  const int tid=threadIdx.x, lane=tid&63, wid=tid>>6;
  const int wm=wid>>1, wn=wid&1, qd=lane>>4, lr=lane&15;
  const int m0=blockIdx.y*64;
  const int k0=blockIdx.x*192;
  const int r_=tid>>2, kg_=tid&3;
  const u16* Ap  = A  + (size_t)(m0+r_)*1536 + k0 + kg_*8;
  const u16* Bp0 = wX + (size_t)r_*1536      + k0 + kg_*8;
  const u16* Bp1 = wX + (size_t)(64+r_)*1536 + k0 + kg_*8;   // tid<128 only
  u16* Asw  = As + r_*40 + kg_*8;
  u16* Bsw0 = Bs + r_*40 + kg_*8;
  u16* Bsw1 = Bs + (64+r_)*40 + kg_*8;
  const bool hasB1 = tid<128;

  v4f acc[2][3];
#pragma unroll
  for(int i=0;i<2;i++)
#pragma unroll
    for(int j=0;j<3;j++) acc[i][j]=v4f{0.f,0.f,0.f,0.f};

  auto domfma=[&](){
    v8s af[2], bfv[3];
#pragma unroll
    for(int i=0;i<2;i++) af[i] =*(const v8s*)(As+(wm*32+i*16+lr)*40+qd*8);
#pragma unroll
    for(int j=0;j<3;j++) bfv[j]=*(const v8s*)(Bs+(wn*48+j*16+lr)*40+qd*8);
#pragma unroll
    for(int i=0;i<2;i++)
#pragma unroll
      for(int j=0;j<3;j++)
        acc[i][j]=__builtin_amdgcn_mfma_f32_16x16x32_bf16(af[i],bfv[j],acc[i][j],0,0,0);
  };

  v8s a0=*(const v8s*)(Ap),    b0x=*(const v8s*)(Bp0),    b0y{};
  v8s a1=*(const v8s*)(Ap+32), b1x=*(const v8s*)(Bp0+32), b1y{};
  if(hasB1){ b0y=*(const v8s*)(Bp1); b1y=*(const v8s*)(Bp1+32); }
  for(int it=0; it<6; it+=2){
    const int kk=it*32;
    __syncthreads();
    *(v8s*)Asw=a0; *(v8s*)Bsw0=b0x; if(hasB1) *(v8s*)Bsw1=b0y;
    __syncthreads();
    if(it+2<6){ a0=*(const v8s*)(Ap+kk+64); b0x=*(const v8s*)(Bp0+kk+64);
      if(hasB1) b0y=*(const v8s*)(Bp1+kk+64); }
    domfma();
    __syncthreads();
    *(v8s*)Asw=a1; *(v8s*)Bsw0=b1x; if(hasB1) *(v8s*)Bsw1=b1y;
    __syncthreads();
    if(it+2<6){ a1=*(const v8s*)(Ap+kk+96); b1x=*(const v8s*)(Bp0+kk+96);
      if(hasB1) b1y=*(const v8s*)(Bp1+kk+96); }
    domfma();
  }

  float* op = xpart + (size_t)blockIdx.x*98304;
#pragma unroll
  for(int i=0;i<2;i++)
#pragma unroll
    for(int j=0;j<3;j++){
      const int gb0=m0+wm*32+i*16+qd*4;
      const int ge =wn*48+j*16+lr;
#pragma unroll
      for(int r=0;r<4;r++)
        op[(size_t)(gb0+r)*96+ge]=acc[i][j][r];
    }
}

// ---------------------------------------------------------------------------
// G3 (+folded sdt): preamble reduces 8 xpart slices for this block's 64 rows
// -> s[b], dt(bf16, LDS); then y = u*(softplus(dt@W_dt^T+bdt)*s + Dp)*zs.
// grid (24 nt, 16 mt) = 384 blocks; K=32 single-shot MFMA.
// ---------------------------------------------------------------------------
__global__ __launch_bounds__(256) void gemm3(
  const float* __restrict__ xpart, const u16* __restrict__ wDt,
  const float* __restrict__ bdt, const float* __restrict__ Dp,
  const u16* __restrict__ u, const u16* __restrict__ zs,
  u16* __restrict__ y)
{
  __shared__ u16 dts[64*40];
  __shared__ u16 Bs[64*40];
  __shared__ float sbl[64];
  const int tid=threadIdx.x, lane=tid&63, wid=tid>>6;
  const int wm=wid>>1, wn=wid&1, qd=lane>>4, lr=lane&15;
  const int m0=blockIdx.y*64, n0=blockIdx.x*64;
  const int r=tid>>2, sub=tid&3;

  // B-tile load issued first, overlaps preamble
  v8s breg = *(const v8s*)(wDt + (size_t)(n0+r)*32 + sub*8);

  // reduce 8 partial slices: thread covers float4 indices {sub+4t}, t=0..5
  float a24[24];
#pragma unroll
  for(int i=0;i<24;i++) a24[i]=0.f;
#pragma unroll
  for(int z=0;z<8;z++){
    const float4* bz=(const float4*)(xpart + (size_t)z*98304 + (size_t)(m0+r)*96);
#pragma unroll
    for(int t=0;t<6;t++){
      float4 v=bz[sub+4*t];
      a24[4*t]+=v.x; a24[4*t+1]+=v.y; a24[4*t+2]+=v.z; a24[4*t+3]+=v.w;
    }
  }
  // s partial: B cols (slots 8..15) x C cols (slots 16..23), aligned pairs
  float s_=0.f;
#pragma unroll
  for(int m=0;m<4;m++) s_ += a24[8+m]*a24[16+m] + a24[12+m]*a24[20+m];
  s_ += __shfl_xor(s_,1); s_ += __shfl_xor(s_,2);
  if(sub==0) sbl[r]=s_;
  v4u p0={ f2bf(a24[0]), f2bf(a24[1]), f2bf(a24[2]), f2bf(a24[3]) };
  v4u p1={ f2bf(a24[4]), f2bf(a24[5]), f2bf(a24[6]), f2bf(a24[7]) };
  *(v4u*)(dts + r*40 + 4*sub)      = p0;
  *(v4u*)(dts + r*40 + 16 + 4*sub) = p1;
  *(v8s*)(Bs + r*40 + sub*8) = breg;
  __syncthreads();

  v4f acc[2][2];
#pragma unroll
  for(int i=0;i<2;i++)
#pragma unroll
    for(int j=0;j<2;j++) acc[i][j]=v4f{0.f,0.f,0.f,0.f};
  v8s af[2], bfv[2];
#pragma unroll
  for(int i=0;i<2;i++) af[i] =*(const v8s*)(dts+(wm*32+i*16+lr)*40+qd*8);
#pragma unroll
  for(int j=0;j<2;j++) bfv[j]=*(const v8s*)(Bs+(wn*32+j*16+lr)*40+qd*8);
#pragma unroll
  for(int i=0;i<2;i++)
#pragma unroll
    for(int j=0;j<2;j++)
      acc[i][j]=__builtin_amdgcn_mfma_f32_16x16x32_bf16(af[i],bfv[j],acc[i][j],0,0,0);

#pragma unroll
  for(int i=0;i<2;i++){
    const int lb0=wm*32+i*16+qd*4;
#pragma unroll
    for(int rr=0;rr<4;rr++){
      const int gb=m0+lb0+rr;
      const float sv=sbl[lb0+rr];
#pragma unroll
      for(int j=0;j<2;j++){
        const int ge=n0+wn*32+j*16+lr;
        float delta=softplusf(acc[i][j][rr]+bdt[ge]);
        float uu=bf2f(u[(size_t)gb*1536+ge]);
        float zz=bf2f(zs[(size_t)gb*1536+ge]);
        y[(size_t)gb*1536+ge]=f2bf(uu*(delta*sv+Dp[ge])*zz);
      }
    }
  }
}

// ---------------------------------------------------------------------------
// G4: y @ W_outproj^T, 32x32 tiles, grid (16 nt, 32 mt) = 512 blocks, full K.
// Epilogue owns final h: h += acc, write hb, atomicAdd next-layer LN stats.
// ---------------------------------------------------------------------------
__global__ __launch_bounds__(256) void gemm4(
  const u16* __restrict__ yv, const u16* __restrict__ wO,
  float* __restrict__ h, u16* __restrict__ hb, float* __restrict__ stn)
{
  __shared__ u16 As[32*40], Bs[32*40];
  const int tid=threadIdx.x, lane=tid&63, wid=tid>>6;
  const int wm=wid>>1, wn=wid&1, qd=lane>>4, lr=lane&15;
  const int m0=blockIdx.y*32, n0=blockIdx.x*32;
  const int half=tid>>7, ts=tid&127;
  const int r_=ts>>2, kg_=ts&3;
  const u16* Gp = (half ? wO + (size_t)(n0+r_)*1536
                        : yv + (size_t)(m0+r_)*1536) + kg_*8;
  u16* Sw = (half ? Bs : As) + r_*40 + kg_*8;

  v4f acc=v4f{0.f,0.f,0.f,0.f};
  auto domfma=[&](){
    v8s af=*(const v8s*)(As+(wm*16+lr)*40+qd*8);
    v8s bf=*(const v8s*)(Bs+(wn*16+lr)*40+qd*8);
    acc=__builtin_amdgcn_mfma_f32_16x16x32_bf16(af,bf,acc,0,0,0);
  };

  v8s g0=*(const v8s*)(Gp), g1=*(const v8s*)(Gp+32);
  for(int it=0; it<48; it+=2){
    const int kk=it*32;
    __syncthreads();
    *(v8s*)Sw=g0;
    __syncthreads();
    if(it+2<48) g0=*(const v8s*)(Gp+kk+64);
    domfma();
    __syncthreads();
    *(v8s*)Sw=g1;
    __syncthreads();
    if(it+2<48) g1=*(const v8s*)(Gp+kk+96);
    domfma();
  }

#pragma unroll
  for(int r=0;r<4;r++){
    const int gb=m0+wm*16+qd*4+r;
    const int ge=n0+wn*16+lr;
    const size_t idx=(size_t)gb*512+ge;
    float hv=h[idx]+acc[r];
    h[idx]=hv; hb[idx]=f2bf(hv);
    float s1=hv, s2=hv*hv;
    s1+=__shfl_xor(s1,1); s2+=__shfl_xor(s2,1);
    s1+=__shfl_xor(s1,2); s2+=__shfl_xor(s2,2);
    s1+=__shfl_xor(s1,4); s2+=__shfl_xor(s2,4);
    s1+=__shfl_xor(s1,8); s2+=__shfl_xor(s2,8);
    if(lr==0){ atomicAdd(stn+gb*2, s1); atomicAdd(stn+gb*2+1, s2); }
  }
}

// ---------------------------------------------------------------------------
// Head: lg/gate/MLP/sigmoid. One block per row.
// ---------------------------------------------------------------------------
__global__ __launch_bounds__(256) void head_kernel(
  const float* __restrict__ x, const float* __restrict__ h,
  const float* __restrict__ wlog, const float* __restrict__ blog,
  const float* __restrict__ wg, const float* __restrict__ bg,
  const float* __restrict__ wh1, const float* __restrict__ bh1,
  const float* __restrict__ wh2, const float* __restrict__ bh2,
  float* __restrict__ out)
{
  int b = blockIdx.x, t = threadIdx.x;
  __shared__ float fused[512];
  __shared__ float part[256];
  __shared__ float z1s[32];
  float lgin = x[b*68+0]*wlog[0] + x[b*68+1]*wlog[1]
             + x[b*68+2]*wlog[2] + x[b*68+3]*wlog[3] + blog[0];
  float lg = 1.f/(1.f+__expf(-lgin));
  for(int d=t; d<512; d+=256)
    fused[d] = h[(size_t)b*512+d]*(lg*wg[d] + bg[d]);
  __syncthreads();
  int j = t&31, c = t>>5;
  float p = 0.f;
#pragma unroll
  for(int i=0;i<64;i++){ int d = c*64+i; p += fused[d]*wh1[j*512+d]; }
  part[t] = p;
  __syncthreads();
  if(t < 32){
    float z = bh1[t];
#pragma unroll
    for(int cc=0; cc<8; cc++) z += part[cc*32+t];
    z1s[t] = fmaxf(z, 0.f);
  }
  __syncthreads();
  if(t==0){
    float lo = bh2[0];
#pragma unroll
    for(int jj=0;jj<32;jj++) lo += z1s[jj]*wh2[jj];
    out[b] = 1.f/(1.f+__expf(-lo));
  }
}

// ---------------------------------------------------------------------------
extern "C" void kernel_launch(void* const* d_in, const int* in_sizes, int n_in,
                              void* d_out, int out_size, void* d_ws, size_t ws_size,
                              hipStream_t stream)
{
  const float* x        = (const float*)d_in[0];
  const float* w_in     = (const float*)d_in[1];
  const float* b_in     = (const float*)d_in[2];
  const float* ln_g     = (const float*)d_in[3];
  const float* ln_b     = (const float*)d_in[4];
  const float* W_inproj = (const float*)d_in[5];
  const float* conv_w   = (const float*)d_in[6];
  const float* conv_b   = (const float*)d_in[7];
  const float* W_xproj  = (const float*)d_in[8];
  const float* W_dt     = (const float*)d_in[9];
  const float* b_dt     = (const float*)d_in[10];
  // d_in[11] A_log: dead — scan is a single step from h0=0
  const float* D_skip   = (const float*)d_in[12];
  const float* W_outproj= (const float*)d_in[13];
  const float* w_log    = (const float*)d_in[14];
  const float* b_log    = (const float*)d_in[15];
  const float* W_gate   = (const float*)d_in[16];
  const float* b_gate   = (const float*)d_in[17];
  const float* W_h1     = (const float*)d_in[18];
  const float* b_h1     = (const float*)d_in[19];
  const float* W_h2     = (const float*)d_in[20];
  const float* b_h2     = (const float*)d_in[21];
  float* out = (float*)d_out;
  (void)in_sizes; (void)n_in; (void)out_size; (void)ws_size;

  char* ws = (char*)d_ws;
  size_t off = 0;
  auto alloc = [&](size_t bytes)->char*{
    char* p = ws + off; off = (off + bytes + 255) & ~(size_t)255; return p; };
  u16*   wIn  = (u16*)  alloc(6291456u*2);   // W' = g*W_inproj, bf16
  u16*   wX   = (u16*)  alloc(589824u*2);
  u16*   wDt  = (u16*)  alloc(196608u*2);
  u16*   wOut = (u16*)  alloc(3145728u*2);
  float* sg   = (float*)alloc(12288u*4);
  float* cb   = (float*)alloc(12288u*4);
  float* stats= (float*)alloc(10240u*4);     // [5][1024][2]
  float* h    = (float*)alloc(524288u*4);
  u16*   hb   = (u16*)  alloc(524288u*2);
  u16*   u    = (u16*)  alloc(1572864u*2);
  u16*   zs   = (u16*)  alloc(1572864u*2);
  u16*   y    = (u16*)  alloc(1572864u*2);
  float* xpart= (float*)alloc(8u*98304u*4);  // G2 split-K partials

  SetupP sp;
  sp.x=x; sp.w_in=w_in; sp.b_in=b_in; sp.ln_g=ln_g; sp.ln_b=ln_b;
  sp.W_inproj=W_inproj; sp.W_xproj=W_xproj; sp.W_dt=W_dt; sp.W_outproj=W_outproj;
  sp.wIn=wIn; sp.wX=wX; sp.wDt=wDt; sp.wOut=wOut;
  sp.sg=sg; sp.cb=cb; sp.stats=stats; sp.h=h; sp.hb=hb;

  setup_kernel<<<14112,256,0,stream>>>(sp);

  for(int l=0;l<4;l++){
    gemm1_ln<<<dim3(48,16),256,0,stream>>>(
      hb, wIn+(size_t)l*1572864, sg+l*3072, cb+l*3072, stats+l*2048,
      conv_w+l*6144, conv_b+l*1536, u, zs);
    gemm2<<<dim3(8,16),256,0,stream>>>(
      u, wX+(size_t)l*147456, xpart);
    gemm3<<<dim3(24,16),256,0,stream>>>(
      xpart, wDt+(size_t)l*49152, b_dt+l*1536, D_skip+l*1536, u, zs, y);
    gemm4<<<dim3(16,32),256,0,stream>>>(
      y, wOut+(size_t)l*786432, h, hb, stats+(l+1)*2048);
  }

  head_kernel<<<1024,256,0,stream>>>(x, h, w_log, b_log, W_gate, b_gate,
                                     W_h1, b_h1, W_h2, b_h2, out);
}

// Round 7
// 288.400 us; speedup vs baseline: 1.6352x; 1.1910x over previous
//
#include <hip/hip_runtime.h>

typedef unsigned short u16;
typedef short v8s __attribute__((ext_vector_type(8)));
typedef float v4f __attribute__((ext_vector_type(4)));
typedef u16  v4u __attribute__((ext_vector_type(4)));

__device__ __forceinline__ float bf2f(u16 h){ return __uint_as_float(((unsigned)h)<<16); }
__device__ __forceinline__ u16 f2bf(float f){
  unsigned u = __float_as_uint(f);
  u += 0x7FFFu + ((u>>16)&1u);
  return (u16)(u>>16);
}
__device__ __forceinline__ float siluf(float x){ return x/(1.f+__expf(-x)); }
__device__ __forceinline__ float softplusf(float x){
  return (x>15.f) ? x : __logf(1.f+__expf(x));
}

// ---------------------------------------------------------------------------
// Setup mega-kernel (3 jobs by block range):
//  [0,9984)      f32->bf16 weight cvt; ln_g folded into W_inproj (W'=g*W)
//  [9984,13056)  prep sg[e]=sum_k g*W, cb[e]=sum_k beta*W
//  [13056,13184) input MLP as MFMA GEMM: h=relu(x[:,4:]@w_in^T+b_in) -> h,hb
//                (coalesced f32->bf16 staging; fixes R6's 64-line/load reads)
// ---------------------------------------------------------------------------
struct SetupP {
  const float *x,*w_in,*b_in,*ln_g,*ln_b,*W_inproj,*W_xproj,*W_dt,*W_outproj;
  u16 *wIn,*wX,*wDt,*wOut;
  float *sg,*cb,*h;
  u16 *hb;
};

__global__ __launch_bounds__(256) void setup_kernel(SetupP sp)
{
  __shared__ u16 As[64*72], Bs[64*72];
  const int blk = blockIdx.x, t = threadIdx.x;
  if(blk < 9984){                        // ---- cvt ----
    const int c0=6291456, c1=c0+589824, c2=c1+196608;
    int i4 = (blk*256 + t)*4;
    float4 v; u16* dst;
    if(i4 < c0){
      v = *(const float4*)(sp.W_inproj + i4);
      int k = i4 & 511, l = (i4>>9)/3072;
      const float* gg = sp.ln_g + l*512 + k;
      v.x*=gg[0]; v.y*=gg[1]; v.z*=gg[2]; v.w*=gg[3];
      dst = sp.wIn + i4;
    } else if(i4 < c1){ int o=i4-c0; v=*(const float4*)(sp.W_xproj+o);   dst=sp.wX+o; }
    else if(i4 < c2){   int o=i4-c1; v=*(const float4*)(sp.W_dt+o);      dst=sp.wDt+o; }
    else {              int o=i4-c2; v=*(const float4*)(sp.W_outproj+o); dst=sp.wOut+o; }
    v4u pk={ f2bf(v.x), f2bf(v.y), f2bf(v.z), f2bf(v.w) };
    *(v4u*)dst = pk;
    return;
  }
  if(blk < 13056){                       // ---- sg/cb prep ----
    int wid=t>>6, lane=t&63;
    int ridx = (blk-9984)*4 + wid;       // l*3072+e
    int l = ridx/3072;
    const float* wr = sp.W_inproj + (size_t)ridx*512;
    const float* gg = sp.ln_g + l*512;
    const float* bb = sp.ln_b + l*512;
    float sgv=0.f, cbv=0.f;
#pragma unroll
    for(int i=0;i<8;i++){ int k=lane*8+i; float w=wr[k]; sgv+=gg[k]*w; cbv+=bb[k]*w; }
#pragma unroll
    for(int off=1; off<64; off<<=1){ sgv+=__shfl_xor(sgv,off); cbv+=__shfl_xor(cbv,off); }
    if(lane==0){ sp.sg[ridx]=sgv; sp.cb[ridx]=cbv; }
    return;
  }
  // ---- input MLP GEMM: 64x64 tile, K=64 (2 MFMA k-steps) ----
  const int mb=blk-13056, mt=mb>>3, nt=mb&7;
  const int m0=mt*64, n0=nt*64;
  const int lane=t&63, wid=t>>6;
  const int wm=wid>>1, wn=wid&1, qd=lane>>4, lr=lane&15;
  const int r=t>>2, cq=t&3;
  {
    const float4* ax=(const float4*)(sp.x + (size_t)(m0+r)*68 + 4 + cq*16);
    const float4* bx=(const float4*)(sp.w_in + (size_t)(n0+r)*64 + cq*16);
    float4 av0=ax[0], av1=ax[1], av2=ax[2], av3=ax[3];
    float4 bv0=bx[0], bv1=bx[1], bv2=bx[2], bv3=bx[3];
    v4u pa0={f2bf(av0.x),f2bf(av0.y),f2bf(av0.z),f2bf(av0.w)};
    v4u pa1={f2bf(av1.x),f2bf(av1.y),f2bf(av1.z),f2bf(av1.w)};
    v4u pa2={f2bf(av2.x),f2bf(av2.y),f2bf(av2.z),f2bf(av2.w)};
    v4u pa3={f2bf(av3.x),f2bf(av3.y),f2bf(av3.z),f2bf(av3.w)};
    v4u pb0={f2bf(bv0.x),f2bf(bv0.y),f2bf(bv0.z),f2bf(bv0.w)};
    v4u pb1={f2bf(bv1.x),f2bf(bv1.y),f2bf(bv1.z),f2bf(bv1.w)};
    v4u pb2={f2bf(bv2.x),f2bf(bv2.y),f2bf(bv2.z),f2bf(bv2.w)};
    v4u pb3={f2bf(bv3.x),f2bf(bv3.y),f2bf(bv3.z),f2bf(bv3.w)};
    u16* aw=As+r*72+cq*16; u16* bw=Bs+r*72+cq*16;
    *(v4u*)(aw)=pa0; *(v4u*)(aw+4)=pa1; *(v4u*)(aw+8)=pa2; *(v4u*)(aw+12)=pa3;
    *(v4u*)(bw)=pb0; *(v4u*)(bw+4)=pb1; *(v4u*)(bw+8)=pb2; *(v4u*)(bw+12)=pb3;
  }
  __syncthreads();
  v4f acc[2][2];
#pragma unroll
  for(int i=0;i<2;i++)
#pragma unroll
    for(int j=0;j<2;j++) acc[i][j]=v4f{0.f,0.f,0.f,0.f};
#pragma unroll
  for(int s=0;s<2;s++){
    v8s af[2], bfv[2];
#pragma unroll
    for(int i=0;i<2;i++) af[i] =*(const v8s*)(As+(wm*32+i*16+lr)*72+s*32+qd*8);
#pragma unroll
    for(int j=0;j<2;j++) bfv[j]=*(const v8s*)(Bs+(wn*32+j*16+lr)*72+s*32+qd*8);
#pragma unroll
    for(int i=0;i<2;i++)
#pragma unroll
      for(int j=0;j<2;j++)
        acc[i][j]=__builtin_amdgcn_mfma_f32_16x16x32_bf16(af[i],bfv[j],acc[i][j],0,0,0);
  }
#pragma unroll
  for(int i=0;i<2;i++)
#pragma unroll
    for(int j=0;j<2;j++){
      const int gb0=m0+wm*32+i*16+qd*4;
      const int ge =n0+wn*32+j*16+lr;
#pragma unroll
      for(int rr=0;rr<4;rr++){
        float hv=fmaxf(acc[i][j][rr]+sp.b_in[ge],0.f);
        const size_t idx=(size_t)(gb0+rr)*512+ge;
        sp.h[idx]=hv; sp.hb[idx]=f2bf(hv);
      }
    }
}

// ---------------------------------------------------------------------------
// G1, algebraic fused LN with in-staging stats: acc = hb @ (g*W)^T;
// S1,S2 accumulated from the very registers staged to LDS (full K=512/row).
// val = rs*(acc - mu*sg) + cb. grid (48,16), BK=64 (8 chunks), depth-2 pf.
// ---------------------------------------------------------------------------
__global__ __launch_bounds__(256) void gemm1_ln(
  const u16* __restrict__ hb, const u16* __restrict__ Wp,
  const float* __restrict__ sg, const float* __restrict__ cb,
  const float* __restrict__ convw, const float* __restrict__ convb,
  u16* __restrict__ u, u16* __restrict__ zs)
{
  __shared__ u16 As[64*72], Bs[64*72];
  __shared__ float sS1[64], sS2[64];
  const int tid=threadIdx.x, lane=tid&63, wid=tid>>6;
  const int wm=wid>>1, wn=wid&1, qd=lane>>4, lr=lane&15;
  const int m0=blockIdx.y*64, n0=blockIdx.x*64;
  const int r_=tid>>2, cq=tid&3;
  const u16* Ap = hb + (size_t)(m0+r_)*512 + cq*16;
  const u16* Bp = Wp + (size_t)(n0+r_)*512 + cq*16;
  u16* Asw = As + r_*72 + cq*16;
  u16* Bsw = Bs + r_*72 + cq*16;

  v4f acc[2][2];
#pragma unroll
  for(int i=0;i<2;i++)
#pragma unroll
    for(int j=0;j<2;j++) acc[i][j]=v4f{0.f,0.f,0.f,0.f};
  float s1=0.f, s2=0.f;

  auto statAcc=[&](v8s v){
#pragma unroll
    for(int e=0;e<8;e++){ float f=bf2f((u16)v[e]); s1+=f; s2+=f*f; }
  };
  auto domfma=[&](){
#pragma unroll
    for(int s=0;s<2;s++){
      v8s af[2], bfv[2];
#pragma unroll
      for(int i=0;i<2;i++) af[i] =*(const v8s*)(As+(wm*32+i*16+lr)*72+s*32+qd*8);
#pragma unroll
      for(int j=0;j<2;j++) bfv[j]=*(const v8s*)(Bs+(wn*32+j*16+lr)*72+s*32+qd*8);
#pragma unroll
      for(int i=0;i<2;i++)
#pragma unroll
        for(int j=0;j<2;j++)
          acc[i][j]=__builtin_amdgcn_mfma_f32_16x16x32_bf16(af[i],bfv[j],acc[i][j],0,0,0);
    }
  };

  v8s a0a=*(const v8s*)(Ap),    a0b=*(const v8s*)(Ap+8);
  v8s b0a=*(const v8s*)(Bp),    b0b=*(const v8s*)(Bp+8);
  v8s a1a=*(const v8s*)(Ap+64), a1b=*(const v8s*)(Ap+72);
  v8s b1a=*(const v8s*)(Bp+64), b1b=*(const v8s*)(Bp+72);
  for(int c=0;c<8;c+=2){
    __syncthreads();
    *(v8s*)Asw=a0a; *(v8s*)(Asw+8)=a0b;
    *(v8s*)Bsw=b0a; *(v8s*)(Bsw+8)=b0b;
    statAcc(a0a); statAcc(a0b);
    __syncthreads();
    if(c+2<8){
      a0a=*(const v8s*)(Ap+(c+2)*64); a0b=*(const v8s*)(Ap+(c+2)*64+8);
      b0a=*(const v8s*)(Bp+(c+2)*64); b0b=*(const v8s*)(Bp+(c+2)*64+8);
    }
    domfma();
    __syncthreads();
    *(v8s*)Asw=a1a; *(v8s*)(Asw+8)=a1b;
    *(v8s*)Bsw=b1a; *(v8s*)(Bsw+8)=b1b;
    statAcc(a1a); statAcc(a1b);
    __syncthreads();
    if(c+3<8){
      a1a=*(const v8s*)(Ap+(c+3)*64); a1b=*(const v8s*)(Ap+(c+3)*64+8);
      b1a=*(const v8s*)(Bp+(c+3)*64); b1b=*(const v8s*)(Bp+(c+3)*64+8);
    }
    domfma();
  }

  // stats: 4 threads (cq=0..3, adjacent lanes) cover a row's 512 cols
  s1+=__shfl_xor(s1,1); s2+=__shfl_xor(s2,1);
  s1+=__shfl_xor(s1,2); s2+=__shfl_xor(s2,2);
  if(cq==0){ sS1[r_]=s1; sS2[r_]=s2; }
  __syncthreads();

#pragma unroll
  for(int i=0;i<2;i++){
    const int lb0=wm*32+i*16+qd*4;
#pragma unroll
    for(int r=0;r<4;r++){
      const int lb=lb0+r, gb=m0+lb;
      float mu=sS1[lb]*(1.f/512.f);
      float rs=rsqrtf(sS2[lb]*(1.f/512.f)-mu*mu+1e-5f);
#pragma unroll
      for(int j=0;j<2;j++){
        const int ge=n0+wn*32+j*16+lr;
        float val = rs*(acc[i][j][r] - mu*sg[ge]) + cb[ge];
        if(ge<1536){
          u[(size_t)gb*1536+ge]=f2bf(siluf(val*convw[ge*4+3]+convb[ge]));
        }else{
          zs[(size_t)gb*1536+(ge-1536)]=f2bf(siluf(val));
        }
      }
    }
  }
}

// ---------------------------------------------------------------------------
// G2: u @ W_xproj^T, split-K=8 -> xpart[z][1024][96]. grid (8 z, 16 mt).
// 64x96 tile, Klen=192 (6 halves, x2-unrolled). (unchanged from R6)
// ---------------------------------------------------------------------------
__global__ __launch_bounds__(256) void gemm2(
  const u16* __restrict__ A, const u16* __restrict__ wX,
  float* __restrict__ xpart)
{
  __shared__ u16 As[64*40];
  __shared__ u16 Bs[96*40];
  const int tid=threadIdx.x, lane=tid&63, wid=tid>>6;
  const int wm=wid>>1, wn=wid&1, qd=lane>>4, lr=lane&15;
  const int m0=blockIdx.y*64;
  const int k0=blockIdx.x*192;
  const int r_=tid>>2, kg_=tid&3;
  const u16* Ap  = A  + (size_t)(m0+r_)*1536 + k0 + kg_*8;
  const u16* Bp0 = wX + (size_t)r_*1536      + k0 + kg_*8;
  const u16* Bp1 = wX + (size_t)(64+r_)*1536 + k0 + kg_*8;
  u16* Asw  = As + r_*40 + kg_*8;
  u16* Bsw0 = Bs + r_*40 + kg_*8;
  u16* Bsw1 = Bs + (64+r_)*40 + kg_*8;
  const bool hasB1 = tid<128;

  v4f acc[2][3];
#pragma unroll
  for(int i=0;i<2;i++)
#pragma unroll
    for(int j=0;j<3;j++) acc[i][j]=v4f{0.f,0.f,0.f,0.f};

  auto domfma=[&](){
    v8s af[2], bfv[3];
#pragma unroll
    for(int i=0;i<2;i++) af[i] =*(const v8s*)(As+(wm*32+i*16+lr)*40+qd*8);
#pragma unroll
    for(int j=0;j<3;j++) bfv[j]=*(const v8s*)(Bs+(wn*48+j*16+lr)*40+qd*8);
#pragma unroll
    for(int i=0;i<2;i++)
#pragma unroll
      for(int j=0;j<3;j++)
        acc[i][j]=__builtin_amdgcn_mfma_f32_16x16x32_bf16(af[i],bfv[j],acc[i][j],0,0,0);
  };

  v8s a0=*(const v8s*)(Ap),    b0x=*(const v8s*)(Bp0),    b0y{};
  v8s a1=*(const v8s*)(Ap+32), b1x=*(const v8s*)(Bp0+32), b1y{};
  if(hasB1){ b0y=*(const v8s*)(Bp1); b1y=*(const v8s*)(Bp1+32); }
  for(int it=0; it<6; it+=2){
    const int kk=it*32;
    __syncthreads();
    *(v8s*)Asw=a0; *(v8s*)Bsw0=b0x; if(hasB1) *(v8s*)Bsw1=b0y;
    __syncthreads();
    if(it+2<6){ a0=*(const v8s*)(Ap+kk+64); b0x=*(const v8s*)(Bp0+kk+64);
      if(hasB1) b0y=*(const v8s*)(Bp1+kk+64); }
    domfma();
    __syncthreads();
    *(v8s*)Asw=a1; *(v8s*)Bsw0=b1x; if(hasB1) *(v8s*)Bsw1=b1y;
    __syncthreads();
    if(it+2<6){ a1=*(const v8s*)(Ap+kk+96); b1x=*(const v8s*)(Bp0+kk+96);
      if(hasB1) b1y=*(const v8s*)(Bp1+kk+96); }
    domfma();
  }

  float* op = xpart + (size_t)blockIdx.x*98304;
#pragma unroll
  for(int i=0;i<2;i++)
#pragma unroll
    for(int j=0;j<3;j++){
      const int gb0=m0+wm*32+i*16+qd*4;
      const int ge =wn*48+j*16+lr;
#pragma unroll
      for(int r=0;r<4;r++)
        op[(size_t)(gb0+r)*96+ge]=acc[i][j][r];
    }
}

// ---------------------------------------------------------------------------
// G3 (+folded sdt): reduce 8 xpart slices -> s[b], dt; then
// y = u*(softplus(dt@W_dt^T+bdt)*s + Dp)*zs. grid (24,16). (unchanged)
// ---------------------------------------------------------------------------
__global__ __launch_bounds__(256) void gemm3(
  const float* __restrict__ xpart, const u16* __restrict__ wDt,
  const float* __restrict__ bdt, const float* __restrict__ Dp,
  const u16* __restrict__ u, const u16* __restrict__ zs,
  u16* __restrict__ y)
{
  __shared__ u16 dts[64*40];
  __shared__ u16 Bs[64*40];
  __shared__ float sbl[64];
  const int tid=threadIdx.x, lane=tid&63, wid=tid>>6;
  const int wm=wid>>1, wn=wid&1, qd=lane>>4, lr=lane&15;
  const int m0=blockIdx.y*64, n0=blockIdx.x*64;
  const int r=tid>>2, sub=tid&3;

  v8s breg = *(const v8s*)(wDt + (size_t)(n0+r)*32 + sub*8);

  float a24[24];
#pragma unroll
  for(int i=0;i<24;i++) a24[i]=0.f;
#pragma unroll
  for(int z=0;z<8;z++){
    const float4* bz=(const float4*)(xpart + (size_t)z*98304 + (size_t)(m0+r)*96);
#pragma unroll
    for(int t=0;t<6;t++){
      float4 v=bz[sub+4*t];
      a24[4*t]+=v.x; a24[4*t+1]+=v.y; a24[4*t+2]+=v.z; a24[4*t+3]+=v.w;
    }
  }
  float s_=0.f;
#pragma unroll
  for(int m=0;m<4;m++) s_ += a24[8+m]*a24[16+m] + a24[12+m]*a24[20+m];
  s_ += __shfl_xor(s_,1); s_ += __shfl_xor(s_,2);
  if(sub==0) sbl[r]=s_;
  v4u p0={ f2bf(a24[0]), f2bf(a24[1]), f2bf(a24[2]), f2bf(a24[3]) };
  v4u p1={ f2bf(a24[4]), f2bf(a24[5]), f2bf(a24[6]), f2bf(a24[7]) };
  *(v4u*)(dts + r*40 + 4*sub)      = p0;
  *(v4u*)(dts + r*40 + 16 + 4*sub) = p1;
  *(v8s*)(Bs + r*40 + sub*8) = breg;
  __syncthreads();

  v4f acc[2][2];
#pragma unroll
  for(int i=0;i<2;i++)
#pragma unroll
    for(int j=0;j<2;j++) acc[i][j]=v4f{0.f,0.f,0.f,0.f};
  v8s af[2], bfv[2];
#pragma unroll
  for(int i=0;i<2;i++) af[i] =*(const v8s*)(dts+(wm*32+i*16+lr)*40+qd*8);
#pragma unroll
  for(int j=0;j<2;j++) bfv[j]=*(const v8s*)(Bs+(wn*32+j*16+lr)*40+qd*8);
#pragma unroll
  for(int i=0;i<2;i++)
#pragma unroll
    for(int j=0;j<2;j++)
      acc[i][j]=__builtin_amdgcn_mfma_f32_16x16x32_bf16(af[i],bfv[j],acc[i][j],0,0,0);

#pragma unroll
  for(int i=0;i<2;i++){
    const int lb0=wm*32+i*16+qd*4;
#pragma unroll
    for(int rr=0;rr<4;rr++){
      const int gb=m0+lb0+rr;
      const float sv=sbl[lb0+rr];
#pragma unroll
      for(int j=0;j<2;j++){
        const int ge=n0+wn*32+j*16+lr;
        float delta=softplusf(acc[i][j][rr]+bdt[ge]);
        float uu=bf2f(u[(size_t)gb*1536+ge]);
        float zz=bf2f(zs[(size_t)gb*1536+ge]);
        y[(size_t)gb*1536+ge]=f2bf(uu*(delta*sv+Dp[ge])*zz);
      }
    }
  }
}

// ---------------------------------------------------------------------------
// G4: y @ W_outproj^T, 32x32 tiles, grid (16,32)=512 blocks, full K=1536
// as 24 BK=64 chunks, depth-2 prefetch. Epilogue: h += acc, write hb.
// ---------------------------------------------------------------------------
__global__ __launch_bounds__(256) void gemm4(
  const u16* __restrict__ yv, const u16* __restrict__ wO,
  float* __restrict__ h, u16* __restrict__ hb)
{
  __shared__ u16 As[32*72], Bs[32*72];
  const int tid=threadIdx.x, lane=tid&63, wid=tid>>6;
  const int wm=wid>>1, wn=wid&1, qd=lane>>4, lr=lane&15;
  const int m0=blockIdx.y*32, n0=blockIdx.x*32;
  const int half=tid>>7, ts=tid&127;
  const int r_=ts>>2, cq=ts&3;
  const u16* Gp = (half ? wO + (size_t)(n0+r_)*1536
                        : yv + (size_t)(m0+r_)*1536) + cq*16;
  u16* Sw = (half ? Bs : As) + r_*72 + cq*16;

  v4f acc=v4f{0.f,0.f,0.f,0.f};
  auto domfma=[&](){
#pragma unroll
    for(int s=0;s<2;s++){
      v8s af=*(const v8s*)(As+(wm*16+lr)*72+s*32+qd*8);
      v8s bf=*(const v8s*)(Bs+(wn*16+lr)*72+s*32+qd*8);
      acc=__builtin_amdgcn_mfma_f32_16x16x32_bf16(af,bf,acc,0,0,0);
    }
  };

  v8s g0a=*(const v8s*)(Gp),    g0b=*(const v8s*)(Gp+8);
  v8s g1a=*(const v8s*)(Gp+64), g1b=*(const v8s*)(Gp+72);
  for(int c=0;c<24;c+=2){
    __syncthreads();
    *(v8s*)Sw=g0a; *(v8s*)(Sw+8)=g0b;
    __syncthreads();
    if(c+2<24){ g0a=*(const v8s*)(Gp+(c+2)*64); g0b=*(const v8s*)(Gp+(c+2)*64+8); }
    domfma();
    __syncthreads();
    *(v8s*)Sw=g1a; *(v8s*)(Sw+8)=g1b;
    __syncthreads();
    if(c+3<24){ g1a=*(const v8s*)(Gp+(c+3)*64); g1b=*(const v8s*)(Gp+(c+3)*64+8); }
    domfma();
  }

#pragma unroll
  for(int r=0;r<4;r++){
    const int gb=m0+wm*16+qd*4+r;
    const int ge=n0+wn*16+lr;
    const size_t idx=(size_t)gb*512+ge;
    float hv=h[idx]+acc[r];
    h[idx]=hv; hb[idx]=f2bf(hv);
  }
}

// ---------------------------------------------------------------------------
// Head: lg/gate/MLP/sigmoid. One block per row.
// ---------------------------------------------------------------------------
__global__ __launch_bounds__(256) void head_kernel(
  const float* __restrict__ x, const float* __restrict__ h,
  const float* __restrict__ wlog, const float* __restrict__ blog,
  const float* __restrict__ wg, const float* __restrict__ bg,
  const float* __restrict__ wh1, const float* __restrict__ bh1,
  const float* __restrict__ wh2, const float* __restrict__ bh2,
  float* __restrict__ out)
{
  int b = blockIdx.x, t = threadIdx.x;
  __shared__ float fused[512];
  __shared__ float part[256];
  __shared__ float z1s[32];
  float lgin = x[b*68+0]*wlog[0] + x[b*68+1]*wlog[1]
             + x[b*68+2]*wlog[2] + x[b*68+3]*wlog[3] + blog[0];
  float lg = 1.f/(1.f+__expf(-lgin));
  for(int d=t; d<512; d+=256)
    fused[d] = h[(size_t)b*512+d]*(lg*wg[d] + bg[d]);
  __syncthreads();
  int j = t&31, c = t>>5;
  float p = 0.f;
#pragma unroll
  for(int i=0;i<64;i++){ int d = c*64+i; p += fused[d]*wh1[j*512+d]; }
  part[t] = p;
  __syncthreads();
  if(t < 32){
    float z = bh1[t];
#pragma unroll
    for(int cc=0; cc<8; cc++) z += part[cc*32+t];
    z1s[t] = fmaxf(z, 0.f);
  }
  __syncthreads();
  if(t==0){
    float lo = bh2[0];
#pragma unroll
    for(int jj=0;jj<32;jj++) lo += z1s[jj]*wh2[jj];
    out[b] = 1.f/(1.f+__expf(-lo));
  }
}

// ---------------------------------------------------------------------------
extern "C" void kernel_launch(void* const* d_in, const int* in_sizes, int n_in,
                              void* d_out, int out_size, void* d_ws, size_t ws_size,
                              hipStream_t stream)
{
  const float* x        = (const float*)d_in[0];
  const float* w_in     = (const float*)d_in[1];
  const float* b_in     = (const float*)d_in[2];
  const float* ln_g     = (const float*)d_in[3];
  const float* ln_b     = (const float*)d_in[4];
  const float* W_inproj = (const float*)d_in[5];
  const float* conv_w   = (const float*)d_in[6];
  const float* conv_b   = (const float*)d_in[7];
  const float* W_xproj  = (const float*)d_in[8];
  const float* W_dt     = (const float*)d_in[9];
  const float* b_dt     = (const float*)d_in[10];
  // d_in[11] A_log: dead — scan is a single step from h0=0
  const float* D_skip   = (const float*)d_in[12];
  const float* W_outproj= (const float*)d_in[13];
  const float* w_log    = (const float*)d_in[14];
  const float* b_log    = (const float*)d_in[15];
  const float* W_gate   = (const float*)d_in[16];
  const float* b_gate   = (const float*)d_in[17];
  const float* W_h1     = (const float*)d_in[18];
  const float* b_h1     = (const float*)d_in[19];
  const float* W_h2     = (const float*)d_in[20];
  const float* b_h2     = (const float*)d_in[21];
  float* out = (float*)d_out;
  (void)in_sizes; (void)n_in; (void)out_size; (void)ws_size;

  char* ws = (char*)d_ws;
  size_t off = 0;
  auto alloc = [&](size_t bytes)->char*{
    char* p = ws + off; off = (off + bytes + 255) & ~(size_t)255; return p; };
  u16*   wIn  = (u16*)  alloc(6291456u*2);   // W' = g*W_inproj, bf16
  u16*   wX   = (u16*)  alloc(589824u*2);
  u16*   wDt  = (u16*)  alloc(196608u*2);
  u16*   wOut = (u16*)  alloc(3145728u*2);
  float* sg   = (float*)alloc(12288u*4);
  float* cb   = (float*)alloc(12288u*4);
  float* h    = (float*)alloc(524288u*4);
  u16*   hb   = (u16*)  alloc(524288u*2);
  u16*   u    = (u16*)  alloc(1572864u*2);
  u16*   zs   = (u16*)  alloc(1572864u*2);
  u16*   y    = (u16*)  alloc(1572864u*2);
  float* xpart= (float*)alloc(8u*98304u*4);  // G2 split-K partials

  SetupP sp;
  sp.x=x; sp.w_in=w_in; sp.b_in=b_in; sp.ln_g=ln_g; sp.ln_b=ln_b;
  sp.W_inproj=W_inproj; sp.W_xproj=W_xproj; sp.W_dt=W_dt; sp.W_outproj=W_outproj;
  sp.wIn=wIn; sp.wX=wX; sp.wDt=wDt; sp.wOut=wOut;
  sp.sg=sg; sp.cb=cb; sp.h=h; sp.hb=hb;

  setup_kernel<<<13184,256,0,stream>>>(sp);

  for(int l=0;l<4;l++){
    gemm1_ln<<<dim3(48,16),256,0,stream>>>(
      hb, wIn+(size_t)l*1572864, sg+l*3072, cb+l*3072,
      conv_w+l*6144, conv_b+l*1536, u, zs);
    gemm2<<<dim3(8,16),256,0,stream>>>(
      u, wX+(size_t)l*147456, xpart);
    gemm3<<<dim3(24,16),256,0,stream>>>(
      xpart, wDt+(size_t)l*49152, b_dt+l*1536, D_skip+l*1536, u, zs, y);
    gemm4<<<dim3(16,32),256,0,stream>>>(
      y, wOut+(size_t)l*786432, h, hb);
  }

  head_kernel<<<1024,256,0,stream>>>(x, h, w_log, b_log, W_gate, b_gate,
                                     W_h1, b_h1, W_h2, b_h2, out);
}